// Round 1
// 60.096 us; speedup vs baseline: 1.0003x; 1.0003x over previous
//
#include <hip/hip_runtime.h>
#include <hip/hip_bf16.h>

// Problem constants (from reference)
#define NN 32
#define K_TOTAL 4
#define RESOLUTION 64
#define KNOTS (NN * RESOLUTION + 1)   // 2049
#define BATCH 256
#define HEAD 2048                      // KNOTS - 1; last c_eff element never contributes
#define OUT_TOTAL (BATCH * NN * K_TOTAL)  // 32768

// Closed form:
//   out[b,n,k] = r*P1[m] - P2[m]/64 + init_val
// where r = mod(t[b,k] - n, 32)  (bit-exact to np.remainder's fp32 path),
//       m = #{ j in [0,2048) : j < 64*r }  (64*r exact: power-of-two scale),
//       P1[m] = sum_{j<m} c[j],  P2[m] = sum_{j<m} j*c[j].
// fp64 accumulation kills the 2048-term cancellation (absmax 0.0 vs ref).
//
// R3 changes (latency polish; arithmetic order unchanged -> bitwise-identical
// output):
//  - P1/P2 interleaved as float2 with +2 padding per 64 entries:
//      idx(m) = m + 2*(m>>6)
//    Within a wave the 16 lanes sharing k have m spaced exactly 64 floats
//    (same bank, 16-way conflict before); padded stride 66*8B -> bank stride 4
//    -> 2 lanes/bank (free). One ds_read_b64 replaces two conflicted b32 reads.
//  - wbase = idx(t*8) is always even -> the 8 float2 table writes are 16B
//    aligned and consecutive -> 4x ds_write_b128 instead of 16x b32.
//  - t_k / init_val loads hoisted to kernel entry so their global latency
//    hides under the fp64 scan instead of sitting on the post-barrier tail.
//  - wave totals published as double2 (one b128 store / fewer b64 reads).

#define PAD_IDX(m) ((m) + (((m) >> 6) << 1))          // +2 per 64 entries
#define PTAB_SIZE (KNOTS + (((KNOTS) >> 6) << 1))     // 2049 + 64 = 2113

__global__ __launch_bounds__(256) void fused_kernel(const float* __restrict__ t_k,
                                                    const float* __restrict__ c_relu,
                                                    const float* __restrict__ init_val,
                                                    float* __restrict__ out) {
    __shared__ float2 P[PTAB_SIZE];
    __shared__ double2 wtot[4];

    const int t = threadIdx.x;
    const int lane = t & 63;
    const int wave = t >> 6;
    const int base = t * 8;   // 256 threads * 8 = 2048 head elements

    // ---- issue ALL global loads up front; latency hides under the scan ----
    const int o = blockIdx.x * 256 + t;        // 0..32767
    const int k = o & (K_TOTAL - 1);
    const int n = (o >> 2) & (NN - 1);
    const int b = o >> 7;
    const float tv = t_k[(b << 2) | k];
    const float iv = init_val[0];

    // coalesced float4 loads of the head coefficients
    const float4* __restrict__ c4 = (const float4*)c_relu;
    const float4 ca = c4[2 * t];
    const float4 cb = c4[2 * t + 1];
    const float c[8] = {ca.x, ca.y, ca.z, ca.w, cb.x, cb.y, cb.z, cb.w};

    // thread-local exclusive prefixes (fp64) — same op order as R2
    double pre1[8], pre2[8];
    double l1 = 0.0, l2 = 0.0;
#pragma unroll
    for (int i = 0; i < 8; ++i) {
        pre1[i] = l1;
        pre2[i] = l2;
        l1 += (double)c[i];
        l2 += (double)(base + i) * (double)c[i];
    }
    const double own1 = l1, own2 = l2;

    // wave-level inclusive scan over the 64 chunk totals (no barriers)
#pragma unroll
    for (int d = 1; d < 64; d <<= 1) {
        const double y1 = __shfl_up(l1, d);
        const double y2 = __shfl_up(l2, d);
        if (lane >= d) { l1 += y1; l2 += y2; }
    }

    // cross-wave combine: lane 63 publishes wave totals
    if (lane == 63) { wtot[wave] = make_double2(l1, l2); }
    __syncthreads();   // barrier 1

    double woff1 = 0.0, woff2 = 0.0;
#pragma unroll
    for (int w = 0; w < 3; ++w) {
        if (wave > w) { woff1 += wtot[w].x; woff2 += wtot[w].y; }
    }

    // exclusive offset for this thread's chunk
    const double off1 = woff1 + (l1 - own1);
    const double off2 = woff2 + (l2 - own2);

    const int wbase = PAD_IDX(base);   // even; 8 entries stay inside one 64-chunk
#pragma unroll
    for (int i = 0; i < 8; ++i) {
        P[wbase + i] = make_float2((float)(off1 + pre1[i]),
                                   (float)(off2 + pre2[i]));
    }
    if (t == 255) {   // grand totals -> last table entry
        P[PAD_IDX(HEAD)] = make_float2((float)(woff1 + l1),
                                       (float)(woff2 + l2));
    }
    __syncthreads();   // barrier 2

    // evaluate this block's 256 outputs
    float r = tv - (float)n;                   // same single fp32 subtract as ref
    if (r < 0.0f) r += 32.0f;                  // np.remainder correction, one rounding

    const float d = r * 64.0f;                 // exact (power-of-two scale)
    int m = (int)d;
    if ((float)m < d) ++m;                     // m = ceil(d): strict j < d
    if (m > HEAD) m = HEAD;                    // safety clamp

    const float2 p = P[PAD_IDX(m)];            // one b64 gather, ~2 lanes/bank
    out[o] = r * p.x - p.y * 0.015625f + iv;   // identical expression to R2
}

extern "C" void kernel_launch(void* const* d_in, const int* in_sizes, int n_in,
                              void* d_out, int out_size, void* d_ws, size_t ws_size,
                              hipStream_t stream) {
    const float* t_k_hat  = (const float*)d_in[0];  // (256,4)
    const float* c_relu   = (const float*)d_in[1];  // (2049,)
    // d_in[2] = shift : analytically -(j/64), folded into the closed form
    const float* init_val = (const float*)d_in[3];  // (1,)
    float* out = (float*)d_out;                     // (256,32,4) fp32

    fused_kernel<<<OUT_TOTAL / 256, 256, 0, stream>>>(t_k_hat, c_relu, init_val, out);
}